// Round 1
// 196.516 us; speedup vs baseline: 1.2377x; 1.2377x over previous
//
#include <hip/hip_runtime.h>

#define NCOLS 65536
#define NROWS 256
#define HID 64

// g3(p,s) lookup table: p in [-0.5,0.5] x s in [0,1)
#define TP 128            // p grid points
#define TS 96             // s grid points
#define TST 100           // padded LDS row stride in words (100%32=4 -> rows spread banks, float4-aligned)
#define PSCALE 127.0f     // TP-1
#define SSCALE 95.0f      // TS-1

#define CPB 512           // cols per block (2 per thread)
#define RPB 32            // rows per block
#define THREADS 256

// ---- builder: exact MLP evaluated on the (p,s) grid with ib = i_b[0] ----
__global__ void soen_build(const float* __restrict__ i_b, const float* __restrict__ w1,
                           const float* __restrict__ b1, const float* __restrict__ w2,
                           const float* __restrict__ b2, float* __restrict__ tabg)
{
    const int e = blockIdx.x * blockDim.x + threadIdx.x;   // grid sized exactly TP*TS
    const int ip = e / TS;
    const int is = e - ip * TS;
    const float p  = -0.5f + (float)ip * (1.0f / PSCALE);
    const float sv = (float)is * (1.0f / SSCALE);
    const float ib = i_b[0];
    float acc = b2[0];
    #pragma unroll 4
    for (int j = 0; j < HID; j++) {
        const float a = fmaf(p, w1[j], fmaf(sv, w1[HID + j], fmaf(ib, w1[2 * HID + j], b1[j])));
        // tanh(a) = 1 - 2/(1+exp2(2*log2e*a))  (same numerics as the previously-passing kernel)
        const float ex = __builtin_amdgcn_exp2f(2.8853900817779268f * a);
        const float th = 1.0f - 2.0f * __builtin_amdgcn_rcpf(1.0f + ex);
        acc = fmaf(w2[j], th, acc);
    }
    tabg[e] = acc;
}

__device__ __forceinline__ float soen_elem(float phv, float svv, int idx, float ibl, float ib0,
        const float* __restrict__ tab,
        const float* __restrict__ w1, const float* __restrict__ b1,
        const float* __restrict__ w2, const float* __restrict__ b2)
{
    const float p = phv - rintf(phv);                      // half-to-even, matches jnp.round
    if (idx == 3) {
        if (__builtin_expect(ibl == ib0, 1)) {
            // bilinear lookup
            const float u  = fmaf(p, PSCALE, 0.5f * PSCALE);   // [0,127]
            const float vv = svv * SSCALE;                     // [0,95)
            int iu = (int)u;  iu = iu > TP - 2 ? TP - 2 : iu;
            int iv = (int)vv; iv = iv > TS - 2 ? TS - 2 : iv;
            const float du = u - (float)iu;
            const float dv = vv - (float)iv;
            const float* b = tab + iu * TST + iv;
            const float t00 = b[0],   t01 = b[1];
            const float t10 = b[TST], t11 = b[TST + 1];
            const float a0 = fmaf(dv, t01 - t00, t00);
            const float a1 = fmaf(dv, t11 - t10, t10);
            return fmaf(du, a1 - a0, a0);
        } else {
            // exact fallback (never taken when i_b is uniform; preserves general correctness)
            float acc = b2[0];
            for (int j = 0; j < HID; j++) {
                const float a = fmaf(p, w1[j], fmaf(svv, w1[HID + j], fmaf(ibl, w1[2 * HID + j], b1[j])));
                const float ex = __builtin_amdgcn_exp2f(2.8853900817779268f * a);
                const float th = 1.0f - 2.0f * __builtin_amdgcn_rcpf(1.0f + ex);
                acc = fmaf(w2[j], th, acc);
            }
            return acc;
        }
    }
    const float p2 = p * p;
    const float g0 = fmaxf(fabsf(p) - svv, 0.f);
    // tanh(p), |p|<=0.5, odd series err<5e-4 (identical to passing kernel)
    const float tp = p * fmaf(p2, fmaf(p2, 0.13333333f, -0.33333333f), 1.f);
    const float g1 = fmaf(-tp, svv, tp);
    const float g2 = __builtin_amdgcn_exp2f(-14.426950408889634f * p2) - svv;
    return (idx == 0) ? g0 : (idx == 1) ? g1 : g2;
}

__global__ __launch_bounds__(THREADS) void soen_main(
    const float* __restrict__ phi, const float* __restrict__ s,
    const float* __restrict__ i_b, const float* __restrict__ w1,
    const float* __restrict__ b1, const float* __restrict__ w2,
    const float* __restrict__ b2, const int* __restrict__ func_idx,
    const float* __restrict__ tabg, float* __restrict__ out)
{
    __shared__ float tab[TP * TST];                        // 51.2 KB -> 3 blocks/CU

    const int t = threadIdx.x;
    // stage table (12288 floats = 3072 float4 = 12 iters), global linear -> padded LDS
    for (int i = t; i < TP * TS / 4; i += THREADS) {
        const float4 v = ((const float4*)tabg)[i];
        const int e = i << 2;
        const int r = e / TS;
        const int c = e - r * TS;                          // multiple of 4 (TS%4==0)
        *(float4*)&tab[r * TST + c] = v;                   // aligned: TST%4==0
    }

    const int col = blockIdx.x * CPB + (t << 1);
    const int rowbase = blockIdx.y * RPB;
    const int2   fidx = *(const int2*)(func_idx + col);
    const float2 ib2  = *(const float2*)(i_b + col);
    const float  ib0  = i_b[0];

    const float2* pp = (const float2*)(phi + (size_t)rowbase * NCOLS) + (col >> 1);
    const float2* sp = (const float2*)(s   + (size_t)rowbase * NCOLS) + (col >> 1);
    float2*       po = (float2*)(out + (size_t)rowbase * NCOLS) + (col >> 1);
    const int STR = NCOLS / 2;

    __syncthreads();

    for (int r0 = 0; r0 < RPB; r0 += 4) {
        float2 ph[4], sv[4];
        #pragma unroll
        for (int k = 0; k < 4; k++) {                      // issue 8 loads (2 KB/wave) up front
            ph[k] = pp[(size_t)(r0 + k) * STR];
            sv[k] = sp[(size_t)(r0 + k) * STR];
        }
        #pragma unroll
        for (int k = 0; k < 4; k++) {
            float2 o;
            o.x = soen_elem(ph[k].x, sv[k].x, fidx.x, ib2.x, ib0, tab, w1, b1, w2, b2);
            o.y = soen_elem(ph[k].y, sv[k].y, fidx.y, ib2.y, ib0, tab, w1, b1, w2, b2);
            po[(size_t)(r0 + k) * STR] = o;
        }
    }
}

extern "C" void kernel_launch(void* const* d_in, const int* in_sizes, int n_in,
                              void* d_out, int out_size, void* d_ws, size_t ws_size,
                              hipStream_t stream)
{
    const float* phi      = (const float*)d_in[0];
    const float* s        = (const float*)d_in[1];
    const float* i_b      = (const float*)d_in[2];
    const float* w1       = (const float*)d_in[3];
    const float* b1       = (const float*)d_in[4];
    const float* w2       = (const float*)d_in[5];
    const float* b2       = (const float*)d_in[6];
    const int*   func_idx = (const int*)d_in[7];
    float* outp = (float*)d_out;
    float* tabg = (float*)d_ws;                            // needs TP*TS*4 = 48 KB of workspace

    soen_build<<<dim3(TP * TS / THREADS), dim3(THREADS), 0, stream>>>(i_b, w1, b1, w2, b2, tabg);

    dim3 grid(NCOLS / CPB, NROWS / RPB);                   // 128 x 8 = 1024 blocks
    soen_main<<<grid, dim3(THREADS), 0, stream>>>(phi, s, i_b, w1, b1, w2, b2, func_idx,
                                                  tabg, outp);
}